// Round 9
// baseline (238.237 us; speedup 1.0000x reference)
//
#include <hip/hip_runtime.h>
#include <math.h>

#define NN 4
#define LL 4096
#define HH 8
#define EE 64
#define CHK 64            // compute chunk rows
#define GSUP 4            // chunks per super-chunk
#define NSUP 16           // supers per (n,h)  (LL / (CHK*GSUP))
#define NH (NN*HH)        // 32
#define NBLK (NH*NSUP)    // 512 blocks == 2/CU * 256 CU  -> all co-resident
#define EPSF 1e-6f

typedef float f32x4 __attribute__((ext_vector_type(4)));
typedef __bf16 bf16x8 __attribute__((ext_vector_type(8)));

__device__ __forceinline__ float phi_map(float x) {
  return x > 0.0f ? x + 1.0f : __expf(x);
}

#define MFMA(a, b, c) __builtin_amdgcn_mfma_f32_16x16x32_bf16((a), (b), (c), 0, 0, 0)

// ---- swizzled [64 rows][64 d] bf16 tile: 16B-block XOR along d (proven 0-conflict) ----
__device__ __forceinline__ int swz64(int row, int d) {
  return row * 64 + (d & 7) + 8 * ((d >> 3) ^ ((row >> 2) & 7));
}
__device__ __forceinline__ int frag64(int row, int blk) {
  return row * 64 + 8 * (blk ^ ((row >> 2) & 7));
}

// ================= reset kernel: zero the lookback flags =================
__global__ void k_reset(int* __restrict__ flags) {
  int i = blockIdx.x * 256 + threadIdx.x;
  if (i < NBLK) flags[i] = 0;
}

// ---- staging macros ----
#define FA_ISSUE(J, BUF) { \
  const int l0i = (sc * GSUP + (J)) * CHK; \
  _Pragma("unroll") for (int it = 0; it < 4; ++it) { \
    int f2 = t + 256 * it; int d = f2 >> 4; int c4 = (f2 & 15) << 2; \
    size_t gb = (((size_t)n * LL + (size_t)(l0i + d)) * HH + h) * EE + c4; \
    pk[BUF][it] = *(const float4*)(Kg + gb); \
    pv[BUF][it] = *(const float4*)(Vg + gb); \
    pl[BUF][it] = KLg[n * LL + l0i + d]; } }

#define FA_STAGE(BUF) { \
  _Pragma("unroll") for (int it = 0; it < 4; ++it) { \
    int f2 = t + 256 * it; int d = f2 >> 4; int c4 = (f2 & 15) << 2; \
    float klr = pl[BUF][it]; float4 kk = pk[BUF][it]; float4 vv = pv[BUF][it]; \
    float ka[4] = {phi_map(kk.x) * klr, phi_map(kk.y) * klr, phi_map(kk.z) * klr, phi_map(kk.w) * klr}; \
    float va[4] = {vv.x, vv.y, vv.z, vv.w}; \
    _Pragma("unroll") for (int jj = 0; jj < 4; ++jj) { \
      sT[BUF][0][swz64(c4 + jj, d)] = (__bf16)ka[jj];   /* K^T [e][d] */ \
      sT[BUF][1][swz64(c4 + jj, d)] = (__bf16)va[jj]; } } }  /* V^T [m][d] */

#define FC_ISSUE(CC, BUF) { \
  const int l0i = (sc * GSUP + (CC)) * CHK; \
  _Pragma("unroll") for (int it = 0; it < 4; ++it) { \
    int f2 = t + 256 * it; int d = f2 >> 4; int c4 = (f2 & 15) << 2; \
    size_t gb = (((size_t)n * LL + (size_t)(l0i + d)) * HH + h) * EE + c4; \
    pk[BUF][it] = *(const float4*)(Kg + gb); \
    pv[BUF][it] = *(const float4*)(Vg + gb); \
    pl[BUF][it] = KLg[n * LL + l0i + d]; } \
  { const float* qr = Qg + (((size_t)n * LL + (size_t)((sc * GSUP + (CC)) * CHK + arow)) * HH + h) * EE; \
    pq[BUF][0] = *(const float4*)(qr + 8 * lg); \
    pq[BUF][1] = *(const float4*)(qr + 8 * lg + 4); \
    pq[BUF][2] = *(const float4*)(qr + 32 + 8 * lg); \
    pq[BUF][3] = *(const float4*)(qr + 32 + 8 * lg + 4); } }

#define FC_STAGE(BUF) { \
  _Pragma("unroll") for (int it = 0; it < 4; ++it) { \
    int f2 = t + 256 * it; int d = f2 >> 4; int c4 = (f2 & 15) << 2; \
    float klr = pl[BUF][it]; float4 kk = pk[BUF][it]; float4 vv = pv[BUF][it]; \
    float ka[4] = {phi_map(kk.x) * klr, phi_map(kk.y) * klr, phi_map(kk.z) * klr, phi_map(kk.w) * klr}; \
    float va[4] = {vv.x, vv.y, vv.z, vv.w}; \
    _Pragma("unroll") for (int jj = 0; jj < 4; ++jj) { \
      sT[BUF][0][swz64(d, c4 + jj)] = (__bf16)ka[jj];   /* K row-major [d][e] */ \
      sT[BUF][1][swz64(c4 + jj, d)] = (__bf16)va[jj]; } } /* V^T [m][d] */ \
  { float4 q0 = pq[BUF][0], q1 = pq[BUF][1], q2 = pq[BUF][2], q3 = pq[BUF][3]; \
    bf16x8 a0, a1; \
    a0[0] = (__bf16)phi_map(q0.x); a0[1] = (__bf16)phi_map(q0.y); \
    a0[2] = (__bf16)phi_map(q0.z); a0[3] = (__bf16)phi_map(q0.w); \
    a0[4] = (__bf16)phi_map(q1.x); a0[5] = (__bf16)phi_map(q1.y); \
    a0[6] = (__bf16)phi_map(q1.z); a0[7] = (__bf16)phi_map(q1.w); \
    a1[0] = (__bf16)phi_map(q2.x); a1[1] = (__bf16)phi_map(q2.y); \
    a1[2] = (__bf16)phi_map(q2.z); a1[3] = (__bf16)phi_map(q2.w); \
    a1[4] = (__bf16)phi_map(q3.x); a1[5] = (__bf16)phi_map(q3.y); \
    a1[6] = (__bf16)phi_map(q3.z); a1[7] = (__bf16)phi_map(q3.w); \
    aQ[BUF][0] = a0; aQ[BUF][1] = a1; } }

// ================= fused kernel: local sums -> lookback prefix -> output =================
__global__ __launch_bounds__(256) void k_fused(
    const float* __restrict__ Qg, const float* __restrict__ Kg,
    const float* __restrict__ Vg, const float* __restrict__ KLg,
    __bf16* __restrict__ Sagg, __bf16* __restrict__ Sinc,
    float* __restrict__ KsAgg, float* __restrict__ KsInc,
    int* flags, float* __restrict__ Og)
{
  __shared__ __bf16 sT[2][2][4096];  // [buf][0:K-layout, 1:V^T]  32 KB
  __shared__ __bf16 sLoc[3][4096];   // frag-order local exclusive S prefixes (chunks 1..3) 24 KB
  __shared__ __bf16 sU[4096];        // S^T tile (swz64); P overlay   8 KB
  __shared__ float sKb[64];          // super-exclusive ksum base
  __shared__ float sKl[4][64];       // local exclusive ksums per chunk
  __shared__ int sFlag;

  const int g = blockIdx.x;          // nh*NSUP + sc
  const int sc = g & (NSUP - 1);
  const int nh = g >> 4;
  const int h = nh % HH;
  const int n = nh / HH;
  const int t = threadIdx.x;
  const int w = t >> 6;
  const int lane = t & 63;
  const int lg = lane >> 4;
  const int li = lane & 15;
  const int arow = 16 * w + li;

  float4 pk[2][4], pv[2][4], pq[2][4];
  float pl[2][4];
  bf16x8 aQ[2][2];

  bf16x8 ones;
  #pragma unroll
  for (int i = 0; i < 8; ++i) ones[i] = (__bf16)1.0f;

  // ================== Phase A: own-super S^T + local exclusive prefixes ==================
  FA_ISSUE(0, 0);
  FA_STAGE(0);

  f32x4 accS[4], accK[4];
  #pragma unroll
  for (int nt = 0; nt < 4; ++nt) {
    accS[nt] = (f32x4){0.f, 0.f, 0.f, 0.f};
    accK[nt] = (f32x4){0.f, 0.f, 0.f, 0.f};
  }

  #pragma unroll
  for (int j = 0; j < GSUP; ++j) {
    if (j + 1 < GSUP) FA_ISSUE(j + 1, (j + 1) & 1);
    __syncthreads();

    // record exclusive locals BEFORE adding chunk j
    if (j > 0) {
      bf16x8 lo, hi;
      #pragma unroll
      for (int k = 0; k < 8; ++k) {
        lo[k] = (__bf16)accS[k >> 2][k & 3];
        hi[k] = (__bf16)accS[2 + (k >> 2)][k & 3];
      }
      *(bf16x8*)&sLoc[j - 1][t * 16] = lo;
      *(bf16x8*)&sLoc[j - 1][t * 16 + 8] = hi;
    }
    if (w == 0 && lg == 0) {
      #pragma unroll
      for (int nt = 0; nt < 4; ++nt)
        sKl[j][li + 16 * nt] = (j > 0) ? accK[nt][0] : 0.0f;
    }

    bf16x8 aV0 = *(const bf16x8*)&sT[j & 1][1][frag64(arow, lg)];
    bf16x8 aV1 = *(const bf16x8*)&sT[j & 1][1][frag64(arow, 4 + lg)];
    #pragma unroll
    for (int nt = 0; nt < 4; ++nt) {
      bf16x8 b0 = *(const bf16x8*)&sT[j & 1][0][frag64(li + 16 * nt, lg)];
      bf16x8 b1 = *(const bf16x8*)&sT[j & 1][0][frag64(li + 16 * nt, 4 + lg)];
      accS[nt] = MFMA(aV0, b0, accS[nt]);
      accS[nt] = MFMA(aV1, b1, accS[nt]);
      if (w == 0) {
        accK[nt] = MFMA(ones, b0, accK[nt]);
        accK[nt] = MFMA(ones, b1, accK[nt]);
      }
    }
    if (j + 1 < GSUP) FA_STAGE((j + 1) & 1);
  }

  // ---- publish aggregate (frag-order, write-once) ----
  {
    bf16x8 lo, hi;
    #pragma unroll
    for (int k = 0; k < 8; ++k) {
      lo[k] = (__bf16)accS[k >> 2][k & 3];
      hi[k] = (__bf16)accS[2 + (k >> 2)][k & 3];
    }
    *(bf16x8*)(Sagg + (size_t)g * 4096 + t * 16) = lo;
    *(bf16x8*)(Sagg + (size_t)g * 4096 + t * 16 + 8) = hi;
  }
  if (w == 0 && lg == 0) {
    #pragma unroll
    for (int nt = 0; nt < 4; ++nt)
      KsAgg[(size_t)g * 64 + li + 16 * nt] = accK[nt][0];
  }
  __threadfence();
  __syncthreads();
  if (t == 0) __hip_atomic_store(&flags[g], 1, __ATOMIC_RELEASE, __HIP_MEMORY_SCOPE_AGENT);

  // issue chunk-0 loads for Phase C; HBM latency hides under the lookback
  FC_ISSUE(0, 0);

  // ================== Lookback: accumulate exclusive base ==================
  float bs[16];
  #pragma unroll
  for (int i = 0; i < 16; ++i) bs[i] = 0.0f;
  float kbv[4] = {0.f, 0.f, 0.f, 0.f};

  if (sc > 0) {
    int p = g - 1;
    const int pmin = g - sc;   // nh*NSUP
    while (true) {
      int f;
      do {
        if (t == 0) sFlag = __hip_atomic_load(&flags[p], __ATOMIC_ACQUIRE, __HIP_MEMORY_SCOPE_AGENT);
        __syncthreads();
        f = sFlag;
        __syncthreads();
      } while (f == 0);
      {
        const __bf16* src = (f == 2 ? Sinc : Sagg) + (size_t)p * 4096 + t * 16;
        const unsigned* su = (const unsigned*)src;
        #pragma unroll
        for (int i2 = 0; i2 < 8; ++i2) {
          unsigned u = __hip_atomic_load((unsigned*)&su[i2], __ATOMIC_RELAXED, __HIP_MEMORY_SCOPE_AGENT);
          bs[2 * i2]     += __uint_as_float(u << 16);
          bs[2 * i2 + 1] += __uint_as_float(u & 0xffff0000u);
        }
        if (w == 0 && lg == 0) {
          const float* ks = (f == 2 ? KsInc : KsAgg) + (size_t)p * 64;
          #pragma unroll
          for (int nt = 0; nt < 4; ++nt)
            kbv[nt] += __hip_atomic_load((float*)&ks[li + 16 * nt], __ATOMIC_RELAXED, __HIP_MEMORY_SCOPE_AGENT);
        }
      }
      if (f == 2) break;
      --p;
      if (p < pmin) break;
    }
  }

  // ---- publish inclusive; stash ksum base to LDS ----
  {
    bf16x8 lo, hi;
    #pragma unroll
    for (int k = 0; k < 8; ++k) {
      lo[k] = (__bf16)(bs[k] + accS[k >> 2][k & 3]);
      hi[k] = (__bf16)(bs[8 + k] + accS[2 + (k >> 2)][k & 3]);
    }
    *(bf16x8*)(Sinc + (size_t)g * 4096 + t * 16) = lo;
    *(bf16x8*)(Sinc + (size_t)g * 4096 + t * 16 + 8) = hi;
  }
  if (w == 0 && lg == 0) {
    #pragma unroll
    for (int nt = 0; nt < 4; ++nt) {
      KsInc[(size_t)g * 64 + li + 16 * nt] = kbv[nt] + accK[nt][0];
      sKb[li + 16 * nt] = kbv[nt];
    }
  }
  __threadfence();
  __syncthreads();
  if (t == 0) __hip_atomic_store(&flags[g], 2, __ATOMIC_RELEASE, __HIP_MEMORY_SCOPE_AGENT);

  // ================== Phase C: per-chunk output (no state-update MFMAs) ==================
  FC_STAGE(0);

  #pragma unroll
  for (int cc = 0; cc < GSUP; ++cc) {
    const int cb = cc & 1, nb2 = cb ^ 1;
    __syncthreads();   // A: FC_STAGE(cc) visible; previous chunk's sU reads done

    if (cc + 1 < GSUP) FC_ISSUE(cc + 1, nb2);

    // build sU = base + local exclusive prefix (own frag positions)
    if (cc == 0) {
      #pragma unroll
      for (int nt = 0; nt < 4; ++nt)
        #pragma unroll
        for (int reg = 0; reg < 4; ++reg)
          sU[swz64(16 * w + 4 * lg + reg, li + 16 * nt)] = (__bf16)bs[nt * 4 + reg];
    } else {
      bf16x8 lo = *(const bf16x8*)&sLoc[cc - 1][t * 16];
      bf16x8 hi = *(const bf16x8*)&sLoc[cc - 1][t * 16 + 8];
      #pragma unroll
      for (int nt = 0; nt < 4; ++nt)
        #pragma unroll
        for (int reg = 0; reg < 4; ++reg) {
          int idx = nt * 4 + reg;
          float lv = (idx < 8) ? (float)lo[idx & 7] : (float)hi[idx & 7];
          sU[swz64(16 * w + 4 * lg + reg, li + 16 * nt)] = (__bf16)(bs[idx] + lv);
        }
    }
    __syncthreads();   // A2: sU complete

    bf16x8 aQ0 = aQ[cb][0], aQ1 = aQ[cb][1];

    // ---- inter: acc = Q * S ----
    f32x4 acc[4];
    #pragma unroll
    for (int nt = 0; nt < 4; ++nt) {
      acc[nt] = (f32x4){0.f, 0.f, 0.f, 0.f};
      bf16x8 b0 = *(const bf16x8*)&sU[frag64(li + 16 * nt, lg)];
      bf16x8 b1 = *(const bf16x8*)&sU[frag64(li + 16 * nt, 4 + lg)];
      acc[nt] = MFMA(aQ0, b0, acc[nt]);
      acc[nt] = MFMA(aQ1, b1, acc[nt]);
    }

    // ---- den = q . (ksum base + local) ----
    float dv = 0.0f;
    #pragma unroll
    for (int i = 0; i < 8; ++i) {
      dv += (float)aQ0[i] * (sKb[8 * lg + i] + sKl[cc][8 * lg + i]);
      dv += (float)aQ1[i] * (sKb[32 + 8 * lg + i] + sKl[cc][32 + 8 * lg + i]);
    }
    dv += __shfl_xor(dv, 16);
    dv += __shfl_xor(dv, 32);
    float den[4];
    #pragma unroll
    for (int reg = 0; reg < 4; ++reg) den[reg] = __shfl(dv, 4 * lg + reg);

    __syncthreads();   // B: all sU inter-reads done -> P may overlay

    // ---- intra: masked attn -> P into sU (wave-own rows) ----
    float rs[4] = {0.f, 0.f, 0.f, 0.f};
    #pragma unroll
    for (int nt = 0; nt < 4; ++nt) {
      f32x4 at2 = (f32x4){0.f, 0.f, 0.f, 0.f};
      if (nt <= w) {
        bf16x8 b0 = *(const bf16x8*)&sT[cb][0][frag64(li + 16 * nt, lg)];
        bf16x8 b1 = *(const bf16x8*)&sT[cb][0][frag64(li + 16 * nt, 4 + lg)];
        at2 = MFMA(aQ0, b0, at2);
        at2 = MFMA(aQ1, b1, at2);
      }
      #pragma unroll
      for (int reg = 0; reg < 4; ++reg) {
        int row = 16 * w + 4 * lg + reg;
        int col = li + 16 * nt;
        float av = (col <= row) ? at2[reg] : 0.0f;
        rs[reg] += av;
        sU[swz64(row, col)] = (__bf16)av;
      }
    }

    #pragma unroll
    for (int reg = 0; reg < 4; ++reg) {
      float v = rs[reg];
      v += __shfl_xor(v, 1);
      v += __shfl_xor(v, 2);
      v += __shfl_xor(v, 4);
      v += __shfl_xor(v, 8);
      rs[reg] = v;
    }

    // ---- PV: acc += P * V (wave-private P rows) ----
    {
      bf16x8 aP0 = *(const bf16x8*)&sU[frag64(arow, lg)];
      bf16x8 aP1 = aP0;
      if (w >= 2) aP1 = *(const bf16x8*)&sU[frag64(arow, 4 + lg)];
      #pragma unroll
      for (int nt = 0; nt < 4; ++nt) {
        bf16x8 bv0 = *(const bf16x8*)&sT[cb][1][frag64(li + 16 * nt, lg)];
        acc[nt] = MFMA(aP0, bv0, acc[nt]);
        if (w >= 2) {
          bf16x8 bv1 = *(const bf16x8*)&sT[cb][1][frag64(li + 16 * nt, 4 + lg)];
          acc[nt] = MFMA(aP1, bv1, acc[nt]);
        }
      }
    }

    // ---- normalize + store ----
    const int l0 = (sc * GSUP + cc) * CHK;
    #pragma unroll
    for (int reg = 0; reg < 4; ++reg) {
      float inv = 1.0f / (den[reg] + rs[reg] + EPSF);
      int row = l0 + 16 * w + 4 * lg + reg;
      size_t ob = (((size_t)n * LL + row) * HH + h) * EE + li;
      #pragma unroll
      for (int nt = 0; nt < 4; ++nt)
        Og[ob + 16 * nt] = acc[nt][reg] * inv;
    }

    if (cc + 1 < GSUP) FC_STAGE(nb2);
  }
}

extern "C" void kernel_launch(void* const* d_in, const int* in_sizes, int n_in,
                              void* d_out, int out_size, void* d_ws, size_t ws_size,
                              hipStream_t stream) {
  const float* Qg  = (const float*)d_in[0];
  const float* Kg  = (const float*)d_in[1];
  const float* Vg  = (const float*)d_in[2];
  const float* KLg = (const float*)d_in[3];
  float* Og = (float*)d_out;

  // ws: Sagg 4MB | Sinc 4MB | KsAgg 128KB | KsInc 128KB | flags 2KB
  char* base = (char*)d_ws;
  __bf16* Sagg = (__bf16*)base;
  __bf16* Sinc = (__bf16*)(base + (size_t)NBLK * 4096 * 2);
  float* KsAgg = (float*)(base + (size_t)NBLK * 4096 * 4);
  float* KsInc = (float*)(base + (size_t)NBLK * 4096 * 4 + (size_t)NBLK * 64 * 4);
  int* flags   = (int*)(base + (size_t)NBLK * 4096 * 4 + (size_t)NBLK * 64 * 8);

  hipLaunchKernelGGL(k_reset, dim3(2), dim3(256), 0, stream, flags);
  hipLaunchKernelGGL(k_fused, dim3(NBLK), dim3(256), 0, stream,
                     Qg, Kg, Vg, KLg, Sagg, Sinc, KsAgg, KsInc, flags, Og);
}

// Round 11
// 47.142 us; speedup vs baseline: 5.0535x; 5.0535x over previous
//
#include <hip/hip_runtime.h>
#include <math.h>

#define NN 4
#define LL 4096
#define HH 8
#define EE 64
#define CHK 64            // compute chunk rows
#define GSUP 4            // chunks per super-chunk
#define NSUP 16           // supers per (n,h)
#define NH (NN*HH)        // 32
#define NBLK (NH*NSUP)    // 512 blocks
#define NCH64 (LL/CHK)    // 64 chunks per (n,h)
#define EPSF 1e-6f

typedef float f32x4 __attribute__((ext_vector_type(4)));
typedef __bf16 bf16x8 __attribute__((ext_vector_type(8)));
typedef __bf16 bf16x4 __attribute__((ext_vector_type(4)));

__device__ __forceinline__ float phi_map(float x) {
  return x > 0.0f ? x + 1.0f : __expf(x);
}

#define MFMA(a, b, c) __builtin_amdgcn_mfma_f32_16x16x32_bf16((a), (b), (c), 0, 0, 0)

// ---- swizzled [64 rows][64 d] bf16 tile: 16B-block XOR along d (proven 0-conflict) ----
__device__ __forceinline__ int swz64(int row, int d) {
  return row * 64 + (d & 7) + 8 * ((d >> 3) ^ ((row >> 2) & 7));
}
__device__ __forceinline__ int frag64(int row, int blk) {
  return row * 64 + 8 * (blk ^ ((row >> 2) & 7));
}

// ================= Kernel 1: per-super S^T = sum_4chunks V^T K (swapped frags); per-chunk ksum =================
#define K1_ISSUE(J, BUF) { \
  const int l0i = (sc * GSUP + (J)) * CHK; \
  _Pragma("unroll") for (int it = 0; it < 4; ++it) { \
    int f = t + 256 * it; int d = f >> 4; int c4 = (f & 15) << 2; \
    size_t gb = (((size_t)n * LL + (size_t)(l0i + d)) * HH + h) * EE + c4; \
    pk[BUF][it] = *(const float4*)(Kg + gb); \
    pv[BUF][it] = *(const float4*)(Vg + gb); \
    pl[BUF][it] = KLg[n * LL + l0i + d]; } }

#define K1_STAGE(BUF) { \
  _Pragma("unroll") for (int it = 0; it < 4; ++it) { \
    int f = t + 256 * it; int d = f >> 4; int c4 = (f & 15) << 2; \
    float klr = pl[BUF][it]; float4 kk = pk[BUF][it]; float4 vv = pv[BUF][it]; \
    float ka[4] = {phi_map(kk.x) * klr, phi_map(kk.y) * klr, phi_map(kk.z) * klr, phi_map(kk.w) * klr}; \
    float va[4] = {vv.x, vv.y, vv.z, vv.w}; \
    _Pragma("unroll") for (int jj = 0; jj < 4; ++jj) { \
      sKt[BUF][swz64(c4 + jj, d)] = (__bf16)ka[jj]; \
      sVt[BUF][swz64(c4 + jj, d)] = (__bf16)va[jj]; } } }

__global__ __launch_bounds__(256, 2) void k_chunksums(
    const float* __restrict__ Kg, const float* __restrict__ Vg,
    const float* __restrict__ KLg, __bf16* __restrict__ ScG, __bf16* __restrict__ KscG)
{
  __shared__ __bf16 sKt[2][4096];   // K^T [e][d]
  __shared__ __bf16 sVt[2][4096];   // V^T [m][d]
  const int g = blockIdx.x;
  const int sc = g & (NSUP - 1);
  const int nh = g >> 4;
  const int h = nh % HH;
  const int n = nh / HH;
  const int t = threadIdx.x;
  const int w = t >> 6;
  const int lane = t & 63;
  const int lg = lane >> 4;
  const int li = lane & 15;
  const int arow = 16 * w + li;

  float4 pk[2][4], pv[2][4];
  float pl[2][4];

  K1_ISSUE(0, 0);
  K1_STAGE(0);

  f32x4 acc[4];   // swapped: acc[nt][reg] = SS[e=16nt+4lg+reg][m=arow]
  #pragma unroll
  for (int nt = 0; nt < 4; ++nt) acc[nt] = (f32x4){0.f, 0.f, 0.f, 0.f};

  bf16x8 ones;
  #pragma unroll
  for (int i = 0; i < 8; ++i) ones[i] = (__bf16)1.0f;

  #pragma unroll
  for (int j = 0; j < GSUP; ++j) {
    if (j + 1 < GSUP) K1_ISSUE(j + 1, (j + 1) & 1);
    __syncthreads();

    bf16x8 bV0 = *(const bf16x8*)&sVt[j & 1][frag64(arow, lg)];
    bf16x8 bV1 = *(const bf16x8*)&sVt[j & 1][frag64(arow, 4 + lg)];

    f32x4 accK[4];
    #pragma unroll
    for (int nt = 0; nt < 4; ++nt) accK[nt] = (f32x4){0.f, 0.f, 0.f, 0.f};

    #pragma unroll
    for (int nt = 0; nt < 4; ++nt) {
      bf16x8 a0 = *(const bf16x8*)&sKt[j & 1][frag64(li + 16 * nt, lg)];
      bf16x8 a1 = *(const bf16x8*)&sKt[j & 1][frag64(li + 16 * nt, 4 + lg)];
      acc[nt] = MFMA(a0, bV0, acc[nt]);     // D[e][m]
      acc[nt] = MFMA(a1, bV1, acc[nt]);
      if (w == 0) {
        accK[nt] = MFMA(ones, a0, accK[nt]);   // col=li -> e=16nt+li
        accK[nt] = MFMA(ones, a1, accK[nt]);
      }
    }
    if (w == 0 && lg == 0) {
      #pragma unroll
      for (int nt = 0; nt < 4; ++nt)
        KscG[(size_t)(g * GSUP + j) * 64 + li + 16 * nt] = (__bf16)accK[nt][0];
    }
    if (j + 1 < GSUP) K1_STAGE((j + 1) & 1);
  }

  // store S^T [m][e] with b64 (4 consecutive e per lane)
  __bf16* sp = ScG + (size_t)g * 4096;
  #pragma unroll
  for (int nt = 0; nt < 4; ++nt) {
    bf16x4 sv;
    #pragma unroll
    for (int reg = 0; reg < 4; ++reg) sv[reg] = (__bf16)acc[nt][reg];
    *(bf16x4*)(sp + arow * 64 + 16 * nt + 4 * lg) = sv;
  }
}

// ================= Kernel 2: exclusive prefixes =================
__global__ __launch_bounds__(256) void k_prefix(
    __bf16* __restrict__ Sc, __bf16* __restrict__ Ksc)
{
  const int bid = blockIdx.x;
  const int t = threadIdx.x;
  if (bid < NH * 16) {
    const int nh = bid >> 4;
    const int strip = bid & 15;
    const int entry = strip * 256 + t;
    __bf16 v[NSUP];
    #pragma unroll
    for (int c = 0; c < NSUP; ++c)
      v[c] = Sc[((size_t)(nh * NSUP + c) << 12) + entry];
    float run = 0.0f;
    #pragma unroll
    for (int c = 0; c < NSUP; ++c) {
      Sc[((size_t)(nh * NSUP + c) << 12) + entry] = (__bf16)run;
      run += (float)v[c];
    }
  } else {
    const int idx = (bid - NH * 16) * 256 + t;
    const int nh = idx >> 6;
    const int e = idx & 63;
    __bf16 v[NCH64];
    #pragma unroll
    for (int c = 0; c < NCH64; ++c)
      v[c] = Ksc[((size_t)(nh * NCH64 + c) << 6) + e];
    float run = 0.0f;
    #pragma unroll
    for (int c = 0; c < NCH64; ++c) {
      Ksc[((size_t)(nh * NCH64 + c) << 6) + e] = (__bf16)run;
      run += (float)v[c];
    }
  }
}

// ================= Kernel 3: swapped-layout pass2, 1 barrier/chunk =================
#define P2_ISSUE(CC) { \
  const int l0i = (sc * GSUP + (CC)) * CHK; \
  _Pragma("unroll") for (int it = 0; it < 4; ++it) { \
    int f = t + 256 * it; int d = f >> 4; int c4 = (f & 15) << 2; \
    size_t gb = (((size_t)n * LL + (size_t)(l0i + d)) * HH + h) * EE + c4; \
    pk[it] = *(const float4*)(Kg + gb); \
    pv[it] = *(const float4*)(Vg + gb); \
    pl[it] = KLg[n * LL + l0i + d]; } \
  { const float* qr = Qg + (((size_t)n * LL + (size_t)(l0i + arow)) * HH + h) * EE; \
    pq[0] = *(const float4*)(qr + 8 * lg); \
    pq[1] = *(const float4*)(qr + 8 * lg + 4); \
    pq[2] = *(const float4*)(qr + 32 + 8 * lg); \
    pq[3] = *(const float4*)(qr + 32 + 8 * lg + 4); } }

#define P2_STAGE(QB) { \
  _Pragma("unroll") for (int it = 0; it < 4; ++it) { \
    int f = t + 256 * it; int d = f >> 4; int c4 = (f & 15) << 2; \
    float klr = pl[it]; float4 kk = pk[it]; float4 vv = pv[it]; \
    float ka[4] = {phi_map(kk.x) * klr, phi_map(kk.y) * klr, phi_map(kk.z) * klr, phi_map(kk.w) * klr}; \
    float va[4] = {vv.x, vv.y, vv.z, vv.w}; \
    bf16x4 kv4; \
    kv4[0] = (__bf16)ka[0]; kv4[1] = (__bf16)ka[1]; kv4[2] = (__bf16)ka[2]; kv4[3] = (__bf16)ka[3]; \
    *(bf16x4*)&sKe[QB][d * 64 + 8 * ((c4 >> 3) ^ ((d >> 2) & 7)) + (c4 & 7)] = kv4; \
    _Pragma("unroll") for (int jj = 0; jj < 4; ++jj) { \
      sKt[QB][swz64(c4 + jj, d)] = (__bf16)ka[jj]; \
      sVt[QB][swz64(c4 + jj, d)] = (__bf16)va[jj]; } } \
  { float4 q0 = pq[0], q1 = pq[1], q2 = pq[2], q3 = pq[3]; \
    bf16x8 a0, a1; \
    a0[0] = (__bf16)phi_map(q0.x); a0[1] = (__bf16)phi_map(q0.y); \
    a0[2] = (__bf16)phi_map(q0.z); a0[3] = (__bf16)phi_map(q0.w); \
    a0[4] = (__bf16)phi_map(q1.x); a0[5] = (__bf16)phi_map(q1.y); \
    a0[6] = (__bf16)phi_map(q1.z); a0[7] = (__bf16)phi_map(q1.w); \
    a1[0] = (__bf16)phi_map(q2.x); a1[1] = (__bf16)phi_map(q2.y); \
    a1[2] = (__bf16)phi_map(q2.z); a1[3] = (__bf16)phi_map(q2.w); \
    a1[4] = (__bf16)phi_map(q3.x); a1[5] = (__bf16)phi_map(q3.y); \
    a1[6] = (__bf16)phi_map(q3.z); a1[7] = (__bf16)phi_map(q3.w); \
    aQ[QB][0] = a0; aQ[QB][1] = a1; } }

__global__ __launch_bounds__(256, 2) void k_pass2(
    const float* __restrict__ Qg, const float* __restrict__ Kg,
    const float* __restrict__ Vg, const float* __restrict__ KLg,
    const __bf16* __restrict__ Sp, const __bf16* __restrict__ Ksp,
    float* __restrict__ Og)
{
  __shared__ __bf16 sKe[2][4096];   // phi(K)*kl [kk][e] swizzled  (attn A)
  __shared__ __bf16 sKt[2][4096];   // K^T [e][d] swizzled         (state A)
  __shared__ __bf16 sVt[2][4096];   // V^T [m][d] swizzled         (PV A / state B)
  __shared__ __bf16 sU[2][4096];    // S^T [m][e] swizzled, double-buffered
  __shared__ __bf16 sP[4][1024];    // per-wave P [16 q][64 kk], row-XOR swizzled

  const int g = blockIdx.x;
  const int sc = g & (NSUP - 1);
  const int nh = g >> 4;
  const int h = nh % HH;
  const int n = nh / HH;
  const int t = threadIdx.x;
  const int w = t >> 6;
  const int lane = t & 63;
  const int lg = lane >> 4;
  const int li = lane & 15;
  const int arow = 16 * w + li;

  float4 pk[4], pv[4], pq[4];
  float pl[4];
  bf16x8 aQ[2][2];

  // ---- stage S^T super-prefix into sU[0] (swz64) ----
  {
    const bf16x8* sp8 = (const bf16x8*)(Sp + (size_t)g * 4096);
    bf16x8 s0 = sp8[2 * t];
    bf16x8 s1 = sp8[2 * t + 1];
    int m = t >> 2, eb = (t & 3) * 2;
    *(bf16x8*)&sU[0][frag64(m, eb)] = s0;
    *(bf16x8*)&sU[0][frag64(m, eb + 1)] = s1;
  }

  // ---- seed state accumulator (swapped frag positions: e=16nt+4lg+reg, m=arow) ----
  f32x4 accS[4];
  #pragma unroll
  for (int nt = 0; nt < 4; ++nt) {
    bf16x4 sv = *(const bf16x4*)(Sp + (size_t)g * 4096 + arow * 64 + 16 * nt + 4 * lg);
    #pragma unroll
    for (int reg = 0; reg < 4; ++reg) accS[nt][reg] = (float)sv[reg];
  }

  P2_ISSUE(0);
  P2_STAGE(0);

  #pragma unroll
  for (int cc = 0; cc < GSUP; ++cc) {
    const int cb = cc & 1, nb = cb ^ 1;
    __syncthreads();   // stage(cc) + sU[cb] writes visible

    if (cc + 1 < GSUP) P2_ISSUE(cc + 1);

    bf16x8 aQ0 = aQ[cb][0], aQ1 = aQ[cb][1];

    // ---- inter (swapped): acc[nt] holds O^T[m=16nt+4lg+reg][q=arow] ----
    f32x4 acc[4];
    #pragma unroll
    for (int nt = 0; nt < 4; ++nt) {
      acc[nt] = (f32x4){0.f, 0.f, 0.f, 0.f};
      bf16x8 aS0 = *(const bf16x8*)&sU[cb][frag64(li + 16 * nt, lg)];
      bf16x8 aS1 = *(const bf16x8*)&sU[cb][frag64(li + 16 * nt, 4 + lg)];
      acc[nt] = MFMA(aS0, aQ0, acc[nt]);
      acc[nt] = MFMA(aS1, aQ1, acc[nt]);
    }

    // ---- den = q . ksum_prefix (per-lane after 2 shfl_xor) ----
    const __bf16* kb = Ksp + (size_t)(g * GSUP + cc) * 64;
    bf16x8 ks0 = *(const bf16x8*)(kb + 8 * lg);
    bf16x8 ks1 = *(const bf16x8*)(kb + 32 + 8 * lg);
    float dv = 0.0f;
    #pragma unroll
    for (int i = 0; i < 8; ++i) {
      dv += (float)aQ0[i] * (float)ks0[i];
      dv += (float)aQ1[i] * (float)ks1[i];
    }
    dv += __shfl_xor(dv, 16);
    dv += __shfl_xor(dv, 32);   // den for q = arow, every lane

    // ---- attn (swapped): lane holds P^T[kk=16nt+4lg+reg][q=arow] ----
    f32x4 at2[4];
    #pragma unroll
    for (int nt = 0; nt < 4; ++nt) at2[nt] = (f32x4){0.f, 0.f, 0.f, 0.f};
    for (int nt = 0; nt <= w; ++nt) {
      bf16x8 aK0 = *(const bf16x8*)&sKe[cb][frag64(li + 16 * nt, lg)];
      bf16x8 aK1 = *(const bf16x8*)&sKe[cb][frag64(li + 16 * nt, 4 + lg)];
      at2[nt] = MFMA(aK0, aQ0, at2[nt]);
      at2[nt] = MFMA(aK1, aQ1, at2[nt]);
    }

    // mask (kk <= q == arow) + pack P rows (wave-private buffer, b64 writes), partial rowsum
    float rs = 0.0f;
    #pragma unroll
    for (int nt = 0; nt < 4; ++nt) {
      bf16x4 pw;
      #pragma unroll
      for (int reg = 0; reg < 4; ++reg) {
        int kk = 16 * nt + 4 * lg + reg;
        float av = (kk <= arow) ? at2[nt][reg] : 0.0f;   // FIXED mask: global kk vs global q
        rs += av;
        pw[reg] = (__bf16)av;
      }
      *(bf16x4*)&sP[w][li * 64 + 8 * ((2 * nt + (lg >> 1)) ^ (li & 7)) + 4 * (lg & 1)] = pw;
    }
    rs += __shfl_xor(rs, 16);
    rs += __shfl_xor(rs, 32);   // full intra rowsum for q = arow

    // ---- PV (swapped): acc += (P V)^T ----
    {
      bf16x8 bP0 = *(const bf16x8*)&sP[w][li * 64 + 8 * (lg ^ (li & 7))];
      bf16x8 bP1 = *(const bf16x8*)&sP[w][li * 64 + 8 * ((4 + lg) ^ (li & 7))];
      #pragma unroll
      for (int nt = 0; nt < 4; ++nt) {
        bf16x8 aV0 = *(const bf16x8*)&sVt[cb][frag64(li + 16 * nt, lg)];
        bf16x8 aV1 = *(const bf16x8*)&sVt[cb][frag64(li + 16 * nt, 4 + lg)];
        acc[nt] = MFMA(aV0, bP0, acc[nt]);
        acc[nt] = MFMA(aV1, bP1, acc[nt]);
      }
    }

    // ---- normalize + float4 store (4 consecutive m per lane) ----
    const int l0 = (sc * GSUP + cc) * CHK;
    {
      float inv = 1.0f / (dv + rs + EPSF);
      size_t ob = (((size_t)n * LL + (size_t)(l0 + arow)) * HH + h) * EE;
      #pragma unroll
      for (int nt = 0; nt < 4; ++nt) {
        float4 o = make_float4(acc[nt][0] * inv, acc[nt][1] * inv,
                               acc[nt][2] * inv, acc[nt][3] * inv);
        *(float4*)(Og + ob + 16 * nt + 4 * lg) = o;
      }
    }

    // ---- state update (swapped): accS += SS_chunk[e][m=arow]; b64 write to sU[nb] ----
    if (cc + 1 < GSUP) {
      bf16x8 bV0 = *(const bf16x8*)&sVt[cb][frag64(arow, lg)];
      bf16x8 bV1 = *(const bf16x8*)&sVt[cb][frag64(arow, 4 + lg)];
      #pragma unroll
      for (int nt = 0; nt < 4; ++nt) {
        bf16x8 aKt0 = *(const bf16x8*)&sKt[cb][frag64(li + 16 * nt, lg)];
        bf16x8 aKt1 = *(const bf16x8*)&sKt[cb][frag64(li + 16 * nt, 4 + lg)];
        accS[nt] = MFMA(aKt0, bV0, accS[nt]);
        accS[nt] = MFMA(aKt1, bV1, accS[nt]);
        bf16x4 sw;
        #pragma unroll
        for (int reg = 0; reg < 4; ++reg) sw[reg] = (__bf16)accS[nt][reg];
        *(bf16x4*)&sU[nb][arow * 64 + 8 * ((2 * nt + (lg >> 1)) ^ ((arow >> 2) & 7)) + 4 * (lg & 1)] = sw;
      }
      P2_STAGE(nb);
    }
  }
}

extern "C" void kernel_launch(void* const* d_in, const int* in_sizes, int n_in,
                              void* d_out, int out_size, void* d_ws, size_t ws_size,
                              hipStream_t stream) {
  const float* Qg  = (const float*)d_in[0];
  const float* Kg  = (const float*)d_in[1];
  const float* Vg  = (const float*)d_in[2];
  const float* KLg = (const float*)d_in[3];
  float* Og = (float*)d_out;

  // ws: Sc bf16 512*4096*2 = 4MB | Ksc bf16 2048*64*2 = 256KB (prefix in place)
  __bf16* Sc  = (__bf16*)d_ws;
  __bf16* Ksc = (__bf16*)((char*)d_ws + (size_t)NBLK * 4096 * 2);

  hipLaunchKernelGGL(k_chunksums, dim3(NBLK), dim3(256), 0, stream, Kg, Vg, KLg, Sc, Ksc);
  hipLaunchKernelGGL(k_prefix, dim3(NH * 16 + 8), dim3(256), 0, stream, Sc, Ksc);
  hipLaunchKernelGGL(k_pass2, dim3(NBLK), dim3(256), 0, stream, Qg, Kg, Vg, KLg, Sc, Ksc, Og);
}